// Round 5
// baseline (162.007 us; speedup 1.0000x reference)
//
#include <hip/hip_runtime.h>
#include <math.h>

// Problem constants (B=8, T=4096, D=1024, G=2, N=320, Cd=512)
#define M_ROWS 32768   // B*T
#define KDIM   1024    // D
#define GN     640     // G*N
#define NGRP   2
#define NCODES 320
#define CD     512

#define BM 64            // rows per block
#define BK 32            // k-tile
#define NT (KDIM / BK)   // 32
#define QBN 160          // cols per block (one quarter of GN)
#define NQ 4
#define QSLAB 10240      // bytes of one (tile, quarter) B slab: 4*160*8*2
#define THREADS 256      // 4 waves, one 16-row slice each

typedef __attribute__((ext_vector_type(8))) short bf16x8;   // 8 bf16 = 4 VGPR
typedef __attribute__((ext_vector_type(4))) float f32x4;

__device__ __forceinline__ unsigned short f2bf(float f) {
    unsigned u = __builtin_bit_cast(unsigned, f);
    return (unsigned short)((u + 0x7FFFu + ((u >> 16) & 1u)) >> 16);  // RNE
}
__device__ __forceinline__ unsigned pk2(float lo, float hi) {
    return (unsigned)f2bf(lo) | ((unsigned)f2bf(hi) << 16);
}
// async global->LDS, 16B/lane; LDS dest = wave-uniform base + lane*16
__device__ __forceinline__ void gll16(const void* g, void* l) {
    __builtin_amdgcn_global_load_lds(
        (const __attribute__((address_space(1))) unsigned int*)g,
        (__attribute__((address_space(3))) unsigned int*)l, 16, 0, 0);
}

// ---- prepass: W[k][GN] fp32 -> Wt3 bf16, laid out as per-(tile,quarter) linear
// 10 KB slabs: Wt3[t][qq][ks][cl][j], k = t*32 + ks*8 + j, col = qq*160 + cl.
// Also zeroes argmax keys and the counts histogram.
__global__ __launch_bounds__(256) void prep_kernel(const float* __restrict__ W,
                                                   unsigned short* __restrict__ Wt3,
                                                   unsigned long long* __restrict__ keys,
                                                   int* __restrict__ counts) {
    const int k = blockIdx.x;                    // 0..1023
    const int t = k >> 5, ks = (k >> 3) & 3, j = k & 7;
    for (int c = threadIdx.x; c < GN; c += 256) {
        int qq = c / QBN, cl = c % QBN;
        Wt3[((((size_t)t * NQ + qq) * 4 + ks) * QBN + cl) * 8 + j] =
            f2bf(W[(size_t)k * GN + c]);
    }
    int gtid = blockIdx.x * 256 + threadIdx.x;
    if (gtid < M_ROWS * NGRP) keys[gtid] = 0ull;
    if (blockIdx.x == 0)
        for (int i = threadIdx.x; i < GN; i += 256) counts[i] = 0;
}

// ---- quarter-width MFMA GEMM + argmax-to-atomicMax.
// 2048 blocks; 4 quarters of each 64-row panel are clustered on one XCD.
__global__ __launch_bounds__(THREADS) void gemm_argmax(
    const float* __restrict__ x,              // [M, K] fp32
    const float* __restrict__ gumbel,         // [M, GN] fp32
    const unsigned short* __restrict__ Wt3,   // retiled bf16 (prep_kernel)
    const float* __restrict__ bias,           // [GN]
    unsigned long long* __restrict__ keys)    // [M, G] packed argmax
{
    __shared__ __align__(16) unsigned short Bs[2][4][QBN][8];  // 20 KB double-buffered

    const int tid  = threadIdx.x;
    const int wid  = tid >> 6;       // 0..3: 16-row slice
    const int lane = tid & 63;
    const int l15  = lane & 15;
    const int l4   = lane >> 4;      // k-slot (8 k-elems each)

    // block decode: bid = xcd + 8*(qq + 4*rt_local); quarters share an XCD
    const int b   = blockIdx.x;
    const int xcd = b & 7;
    const int l   = b >> 3;
    const int qq  = l & 3;                    // column quarter
    const int rt  = xcd * 64 + (l >> 2);      // row tile 0..511
    const int row0 = rt * BM;

    f32x4 acc[10];
#pragma unroll
    for (int nf = 0; nf < 10; ++nf) acc[nf] = (f32x4){0.f, 0.f, 0.f, 0.f};

    // A: direct per-lane register loads; lane owns row (row0+wid*16+l15), k-slice l4*8
    const float* aptr = x + (size_t)(row0 + wid * 16 + l15) * KDIM + l4 * 8;
    // B: per-lane global src (includes lane*16); LDS dst wave-uniform
    const char* bsrc = (const char*)Wt3 + (size_t)qq * QSLAB + (size_t)lane * 16;
    char* BsB = (char*)&Bs[0][0][0][0];

    // prologue: stage tile 0
    for (int s = wid; s < 10; s += 4)
        gll16(bsrc + s * 1024, BsB + s * 1024);
    float4 a0 = *reinterpret_cast<const float4*>(aptr);
    float4 a1 = *reinterpret_cast<const float4*>(aptr + 4);
    __syncthreads();

    for (int t = 0; t < NT; ++t) {
        const int buf = t & 1;
        // issue next tile's B DMA + A loads first: they fly during compute
        float4 n0, n1;
        if (t + 1 < NT) {
            for (int s = wid; s < 10; s += 4)
                gll16(bsrc + (size_t)(t + 1) * (NQ * QSLAB) + s * 1024,
                      BsB + (buf ^ 1) * QSLAB + s * 1024);
            n0 = *reinterpret_cast<const float4*>(aptr + (t + 1) * BK);
            n1 = *reinterpret_cast<const float4*>(aptr + (t + 1) * BK + 4);
        }
        union { bf16x8 v; unsigned u[4]; } w;
        w.u[0] = pk2(a0.x, a0.y); w.u[1] = pk2(a0.z, a0.w);
        w.u[2] = pk2(a1.x, a1.y); w.u[3] = pk2(a1.z, a1.w);
        bf16x8 af = w.v;
#pragma unroll
        for (int nf = 0; nf < 10; ++nf) {
            bf16x8 bfr = *reinterpret_cast<const bf16x8*>(
                BsB + buf * QSLAB + ((l4 * QBN + nf * 16 + l15) * 16));
            acc[nf] = __builtin_amdgcn_mfma_f32_16x16x32_bf16(af, bfr, acc[nf], 0, 0, 0);
        }
        if (t + 1 < NT) { a0 = n0; a1 = n1; }
        __syncthreads();   // drains vmcnt: next tile resident; all waves done with buf
    }

    // ---- epilogue: + bias + gumbel, per-row argmax over this block's 160 cols,
    // then packed 64-bit atomicMax (value<<32 | (319-n): ties pick smaller n).
    float bv[10];
#pragma unroll
    for (int nf = 0; nf < 10; ++nf) bv[nf] = bias[qq * QBN + nf * 16 + l15];
    const int g     = qq >> 1;
    const int nbase = (qq & 1) * QBN;   // n-offset within group
#pragma unroll
    for (int j = 0; j < 4; ++j) {
        const int lr = wid * 16 + l4 * 4 + j;     // C/D layout: row = l4*4 + reg j
        const size_t r = row0 + lr;
        float best = -INFINITY;
        int bn = 0;
#pragma unroll
        for (int nf = 0; nf < 10; ++nf) {
            int n = nbase + nf * 16 + l15;
            float v = acc[nf][j] + bv[nf] + gumbel[r * GN + g * NCODES + n];
            if (v > best) { best = v; bn = n; }   // nf ascending -> first max kept
        }
#pragma unroll
        for (int m = 1; m < 16; m <<= 1) {
            float ov = __shfl_xor(best, m, 64);
            int   on = __shfl_xor(bn, m, 64);
            if (ov > best || (ov == best && on < bn)) { best = ov; bn = on; }
        }
        if (l15 == 0) {
            unsigned ub = __builtin_bit_cast(unsigned, best);
            unsigned su = (ub & 0x80000000u) ? ~ub : (ub | 0x80000000u);
            unsigned long long key =
                ((unsigned long long)su << 32) | (unsigned)(NCODES - 1 - bn);
            atomicMax(&keys[r * NGRP + g], key);
        }
    }
}

// ---- pure-BW gather + histogram: 8 rows per block
__global__ __launch_bounds__(256) void gather_kernel(
    const unsigned long long* __restrict__ keys,
    const float* __restrict__ codebook,
    int* __restrict__ counts,
    float* __restrict__ out)
{
    __shared__ int ns[8][2];
    const int t  = threadIdx.x;
    const int rb = blockIdx.x * 8;
    if (t < 16) {
        int lr = t >> 1, g = t & 1;
        unsigned long long key = keys[(size_t)(rb + lr) * NGRP + g];
        int n = NCODES - 1 - (int)(key & 0xFFFFFFFFull);
        ns[lr][g] = n;
        atomicAdd(&counts[g * NCODES + n], 1);
    }
    __syncthreads();
#pragma unroll
    for (int s = 0; s < 8; ++s) {
        int fi = t + 256 * s;        // 0..2047
        int lr = fi >> 8, q = fi & 255;
        int g = q >> 7, d4 = q & 127;
        int n = ns[lr][g];
        float4 cv = *reinterpret_cast<const float4*>(
            &codebook[((size_t)g * NCODES + n) * CD + d4 * 4]);
        *reinterpret_cast<float4*>(&out[(size_t)(rb + lr) * KDIM + q * 4]) = cv;
    }
}

__global__ void loss_kernel(const int* __restrict__ counts, float* __restrict__ out_loss) {
    __shared__ float red[256];
    float sum = 0.0f;
    for (int i = threadIdx.x; i < GN; i += 256) {
        float avg = (float)counts[i] * (1.0f / (float)M_ROWS);
        sum += avg * logf(avg + 1e-7f);
    }
    red[threadIdx.x] = sum;
    __syncthreads();
    for (int s = 128; s > 0; s >>= 1) {
        if (threadIdx.x < s) red[threadIdx.x] += red[threadIdx.x + s];
        __syncthreads();
    }
    if (threadIdx.x == 0) out_loss[0] = -red[0] * (1.0f / (float)NGRP);
}

extern "C" void kernel_launch(void* const* d_in, const int* in_sizes, int n_in,
                              void* d_out, int out_size, void* d_ws, size_t ws_size,
                              hipStream_t stream) {
    const float* x        = (const float*)d_in[0];
    const float* gumbel   = (const float*)d_in[1];
    const float* codebook = (const float*)d_in[2];
    const float* W        = (const float*)d_in[3];
    const float* bias     = (const float*)d_in[4];
    float* out = (float*)d_out;

    unsigned short* Wt3 = (unsigned short*)d_ws;                         // 1.25 MB
    unsigned long long* keys = (unsigned long long*)((char*)d_ws + 1310720);  // 512 KB
    int* counts = (int*)((char*)d_ws + 1310720 + 524288);                // 2.5 KB

    prep_kernel<<<dim3(KDIM), dim3(256), 0, stream>>>(W, Wt3, keys, counts);
    gemm_argmax<<<dim3(2048), dim3(THREADS), 0, stream>>>(
        x, gumbel, Wt3, bias, keys);
    gather_kernel<<<dim3(M_ROWS / 8), dim3(256), 0, stream>>>(
        keys, codebook, counts, out);
    loss_kernel<<<dim3(1), dim3(256), 0, stream>>>(
        counts, out + (size_t)M_ROWS * KDIM);
}